// Round 11
// baseline (451.017 us; speedup 1.0000x reference)
//
#include <hip/hip_runtime.h>

typedef _Float16 halfx8 __attribute__((ext_vector_type(8)));
typedef _Float16 halfx4 __attribute__((ext_vector_type(4)));
typedef _Float16 halfx2 __attribute__((ext_vector_type(2)));
typedef float floatx4 __attribute__((ext_vector_type(4)));
typedef _Float16 half_t;

#define SEQ    2048
#define NQH    16
#define NKVH   2
#define HD     128
#define QKVN   2560   // 2048 q + 256 k + 256 v
#define VTS    2080   // Vt row stride in halves (4160 B — breaks 4 KB channel aliasing)
#define SLOTS_PER_HEAD 80    // per head: 48 full 512-key chunks + 32 partial chunks

static __device__ __forceinline__ floatx4 mfma16x16x32(halfx8 a, halfx8 b, floatx4 c) {
    return __builtin_amdgcn_mfma_f32_16x16x32_f16(a, b, c, 0, 0, 0);
}

// async global->LDS, 16B per lane (global_load_lds_dwordx4). LDS dest must be
// wave-uniform base + lane*16 (m104) — global source may be arbitrary per-lane.
typedef __attribute__((address_space(3))) unsigned int lds_uint;
typedef const __attribute__((address_space(1))) unsigned int glob_uint;
static __device__ __forceinline__ void async_load16(const void* g, void* l) {
    __builtin_amdgcn_global_load_lds((glob_uint*)g, (lds_uint*)l, 16, 0, 0);
}

// ---------------- merged prep: cvt + transposes + pos_seg + sincos + cnt-zero ----------------
// R10 lesson: workspace is POISON-FILLED between iterations (fillBufferAligned,
// 268 MB) — device-side flags must be explicitly zeroed each run. chunk_cnt for
// attn's atomic combine-tail is zeroed in the pos_seg block.
#define PREP_CVT_BLKS    4096            // hidden f32->f16: 4096*256 float4
#define PREP_T1_BLKS     (80 * 64)       // w_qkv transpose: C/32 x R/32
#define PREP_T2_BLKS     (64 * 64)       // w_o transpose
#define PREP_SC_BLKS     512             // sincos table: 2048 x 64 entries
__global__ __launch_bounds__(256) void prep_kernel(const float* __restrict__ hidden,
                                                   half_t* __restrict__ hiddenH,
                                                   const float* __restrict__ w_qkv,
                                                   half_t* __restrict__ wqkvT,
                                                   const float* __restrict__ w_o,
                                                   half_t* __restrict__ woT,
                                                   const int* __restrict__ praw,
                                                   int* __restrict__ pos_eff,
                                                   int* __restrict__ seg_end,
                                                   float2* __restrict__ sctab,
                                                   int* __restrict__ chunk_cnt) {
    __shared__ float tile[32][33];
    __shared__ int part[256];
    const int t = threadIdx.x;
    int b = blockIdx.x;
    if (b < PREP_CVT_BLKS) {             // ---- fp32 -> fp16 elementwise ----
        int idx = b * 256 + t;
        float4 v = reinterpret_cast<const float4*>(hidden)[idx];
        halfx4 h = {(half_t)v.x, (half_t)v.y, (half_t)v.z, (half_t)v.w};
        reinterpret_cast<halfx4*>(hiddenH)[idx] = h;
        return;
    }
    b -= PREP_CVT_BLKS;
    if (b < PREP_T1_BLKS + PREP_T2_BLKS) {   // ---- transpose f32 -> f16 ----
        const float* in;
        half_t* out;
        int R, C, bx, by;
        if (b < PREP_T1_BLKS) { in = w_qkv; out = wqkvT; R = 2048; C = QKVN; bx = b % 80; by = b / 80; }
        else { b -= PREP_T1_BLKS; in = w_o; out = woT; R = 2048; C = 2048; bx = b & 63; by = b >> 6; }
        const int tx = t & 31, ty = t >> 5;
        const int r0 = by * 32, c0 = bx * 32;
#pragma unroll
        for (int j = 0; j < 4; ++j)
            tile[ty * 4 + j][tx] = in[(size_t)(r0 + ty * 4 + j) * C + c0 + tx];
        __syncthreads();
        // 16B-per-lane writes: thread t<128 owns out-row c0+cc, 8 r-values
        if (t < 128) {
            const int cc = t >> 2, rB = (t & 3) * 8;
            halfx8 v;
#pragma unroll
            for (int j = 0; j < 8; ++j) v[j] = (half_t)tile[rB + j][cc];
            *reinterpret_cast<halfx8*>(&out[(size_t)(c0 + cc) * R + r0 + rB]) = v;
        }
        return;
    }
    b -= PREP_T1_BLKS + PREP_T2_BLKS;
    if (b >= 1) {                        // ---- sincos table: idx = s*64 + i ----
        int idx = (b - 1) * 256 + t;     // [0, 131072)
        int s = idx >> 6, i = idx & 63;
        const bool is64 = (praw[1] == 0 && praw[2] == 1);
        int p = is64 ? praw[2 * s] : praw[s];
        if (p == -1) p = 0;
        float ang = (float)p * exp2f(-(float)i * (19.931568569324174f / 64.0f));
        float sn, cs;
        sincosf(ang, &sn, &cs);
        sctab[idx] = make_float2(cs, sn);
        return;
    }
    // ---- positions + per-position segment end (single block) + cnt zero ----
    chunk_cnt[t] = 0;
    chunk_cnt[t + 256] = 0;
    const bool is64 = (praw[1] == 0 && praw[2] == 1);
    const int BIG = 1 << 29;
    int pv[8];
#pragma unroll
    for (int j = 0; j < 8; ++j) {
        int idx = t * 8 + j;
        int p = is64 ? praw[2 * idx] : praw[idx];
        if (p == -1) p = 0;
        pv[j] = p;
        pos_eff[idx] = p;
    }
    int nmin = BIG;
    int loc[8];
#pragma unroll
    for (int j = 7; j >= 0; --j) {
        loc[j] = nmin;
        if (pv[j] == 0) nmin = t * 8 + j;
    }
    part[t] = nmin;
    __syncthreads();
    for (int off = 1; off < 256; off <<= 1) {
        int v = (t + off < 256) ? part[t + off] : BIG;
        __syncthreads();
        part[t] = min(part[t], v);
        __syncthreads();
    }
    int suffix = (t < 255) ? part[t + 1] : BIG;
#pragma unroll
    for (int j = 0; j < 8; ++j) {
        int nxt = min(loc[j], suffix);
        seg_end[t * 8 + j] = min(nxt, SEQ) - 1;
    }
}

// ---------------- fp16 MFMA GEMM, B^T (N-major), 64x128 (MxN) tile, BK=64 ----------------
// v6: BK=64 + both-sides XOR slot-swizzle. v7: FUSE_ROPE epilogue. v8: sincos
// table + Y-major XCD swizzle. R10 datum: neither GEMM appeared above the
// 41.4 us fill threshold -> both < 41 us (>= ~525 TF) — structure is adequate.
template <bool HAS_BIAS, bool OUT_F16, bool FUSE_ROPE>
__global__ __launch_bounds__(256) void gemm_bt(const half_t* __restrict__ A,
                                               const half_t* __restrict__ BT,
                                               const float* __restrict__ bias,
                                               void* __restrict__ Cout,
                                               int M, int N, int K,
                                               const float2* __restrict__ sctab,
                                               half_t* __restrict__ Kr,
                                               half_t* __restrict__ Vt) {
    __shared__ __align__(16) half_t As[2][64 * 64];    // 16 KB
    __shared__ __align__(16) half_t Bs[2][128 * 64];   // 32 KB
    const int tid = threadIdx.x;
    const int wave = tid >> 6, lane = tid & 63;
    const int lr = lane & 15, quad = lane >> 4;
    // XCD swizzle on linearized block id (nwg multiple of 8: 640, 512).
    // Decode y-major: same-XCD chunk = same bx (B panel) walking by.
    const int nwg = gridDim.x * gridDim.y;
    const int bidl = blockIdx.y * gridDim.x + blockIdx.x;
    const int cpx = nwg >> 3;
    const int swz = (bidl & 7) * cpx + (bidl >> 3);
    const int bx = swz / gridDim.y, by = swz % gridDim.y;
    const int m0 = by * 64, n0 = bx * 128;
    const int rw = (wave & 1) * 32, cw = (wave >> 1) * 64;
    floatx4 acc[2][4] = {};
    auto stage = [&](int kt, int buf) {
        const int k0 = kt * 64;
        // A tile: 64 rows x 8 slots = 512 x 16B
#pragma unroll
        for (int j = 0; j < 2; ++j) {
            int idx = j * 256 + tid;
            int row = idx >> 3, sl = idx & 7;
            async_load16(A + (size_t)(m0 + row) * K + k0 + ((sl ^ (row & 7)) * 8),
                         &As[buf][idx * 8]);
        }
        // B tile: 128 rows x 8 slots = 1024 x 16B
#pragma unroll
        for (int j = 0; j < 4; ++j) {
            int idx = j * 256 + tid;
            int row = idx >> 3, sl = idx & 7;
            async_load16(BT + (size_t)(n0 + row) * K + k0 + ((sl ^ (row & 7)) * 8),
                         &Bs[buf][idx * 8]);
        }
    };
    const int NT = K >> 6;
    stage(0, 0);
    __syncthreads();
    for (int t = 0; t < NT; ++t) {
        const int buf = t & 1;
        if (t + 1 < NT) stage(t + 1, buf ^ 1);   // prefetch lands during MFMA
#pragma unroll
        for (int ks = 0; ks < 2; ++ks) {
            halfx8 af[2], bfr[4];
#pragma unroll
            for (int q2 = 0; q2 < 2; ++q2)
                af[q2] = *reinterpret_cast<const halfx8*>(
                    &As[buf][(rw + q2 * 16 + lr) * 64 + (((ks << 2) + quad) ^ (lr & 7)) * 8]);
#pragma unroll
            for (int q4 = 0; q4 < 4; ++q4)
                bfr[q4] = *reinterpret_cast<const halfx8*>(
                    &Bs[buf][(cw + q4 * 16 + lr) * 64 + (((ks << 2) + quad) ^ (lr & 7)) * 8]);
#pragma unroll
            for (int im = 0; im < 2; ++im)
#pragma unroll
                for (int in = 0; in < 4; ++in)
                    acc[im][in] = mfma16x16x32(af[im], bfr[in], acc[im][in]);
        }
        // single barrier: drains this iter's prefetch + guards buffer reuse
        __syncthreads();
    }
    if (!FUSE_ROPE) {
#pragma unroll
        for (int in = 0; in < 4; ++in) {
            const int col = n0 + cw + in * 16 + lr;
            float bv = 0.0f;
            if (HAS_BIAS) bv = bias[col];
#pragma unroll
            for (int im = 0; im < 2; ++im) {
#pragma unroll
                for (int r = 0; r < 4; ++r) {
                    int rowg = m0 + rw + im * 16 + quad * 4 + r;
                    float v = acc[im][in][r] + bv;
                    if (OUT_F16)
                        ((half_t*)Cout)[(size_t)rowg * N + col] = (half_t)v;
                    else
                        ((float*)Cout)[(size_t)rowg * N + col] = v;
                }
            }
        }
    } else {
        const int region = n0 >> 7;          // 0..15 Q, 16..17 K, 18..19 V (uniform/block)
        int rowg_[2][4];
#pragma unroll
        for (int im = 0; im < 2; ++im)
#pragma unroll
            for (int r = 0; r < 4; ++r)
                rowg_[im][r] = m0 + rw + im * 16 + quad * 4 + r;
#pragma unroll
        for (int in = 0; in < 4; ++in) {
            const int col = n0 + cw + in * 16 + lr;
            const float bv = bias[col];
            if (region < 18) {
                // rope: pair index shared by lanes (lr, lr^1); table load, no trig
                const int fidx = (col & 127) >> 1;
#pragma unroll
                for (int im = 0; im < 2; ++im) {
#pragma unroll
                    for (int r = 0; r < 4; ++r) {
                        float v = acc[im][in][r] + bv;
                        float other = __shfl_xor(v, 1, 64);
                        float2 sc = sctab[rowg_[im][r] * 64 + fidx];
                        float res = (lr & 1) ? (other * sc.y + v * sc.x)
                                             : (v * sc.x - other * sc.y);
                        if (region < 16)
                            ((half_t*)Cout)[(size_t)rowg_[im][r] * N + col] = (half_t)res;
                        else
                            Kr[(size_t)(region - 16) * SEQ * HD +
                               (size_t)rowg_[im][r] * HD + (col & 127)] = (half_t)res;
                    }
                }
            } else {
                // V: raw (biased) values, transposed into Vt[d][s]; pack 4 rows = 8B
                half_t* vb = Vt + (size_t)(region - 18) * HD * VTS + (size_t)(col & 127) * VTS;
#pragma unroll
                for (int im = 0; im < 2; ++im) {
                    halfx4 pk;
#pragma unroll
                    for (int r = 0; r < 4; ++r) pk[r] = (half_t)(acc[im][in][r] + bv);
                    *reinterpret_cast<halfx4*>(&vb[m0 + rw + im * 16 + quad * 4]) = pk;
                }
            }
        }
    }
}

// ---------------- flash attention v8: v5 loop + atomic combine tail ----------------
// Single 1280-block dispatch (R10: 3-way split cost 11 us). After writing its
// partials, each block does store -> __threadfence -> __syncthreads -> tid0
// atomicAdd(chunk_cnt[h*32+qt]); the block bringing the count to nch performs
// the combine for (h,qt) inline (last-arriver pattern; device-scope atomics are
// XCD-safe per G16). Deletes the combine kernel + one launch boundary.
// VGPR watch: tail reuses registers dead after the main loop (aq etc.); if
// VGPR_Count > 128 in counters, occupancy halves (R3 cliff) -> revert signal.
__global__ __launch_bounds__(256) void attn_kernel(const half_t* __restrict__ qkv,
                                                   const half_t* __restrict__ Kr,
                                                   const half_t* __restrict__ Vt,
                                                   const int* __restrict__ seg_end,
                                                   half_t* __restrict__ part_o,
                                                   float* __restrict__ part_l,
                                                   int* __restrict__ chunk_cnt,
                                                   half_t* __restrict__ attnO) {
    __shared__ __align__(16) half_t Ks[2][64 * 128];  // 2x16 KB, XOR-swizzled
    __shared__ __align__(16) half_t Pl[2][64 * 72];   // 2x9 KB, padded stride
    const int tid = threadIdx.x;
    const int wave = tid >> 6, lane = tid & 63;
    const int lr = lane & 15, quad = lane >> 4;
    const int bid = blockIdx.x;
    // dispatch decode: 768 full 8-tile chunks first, then partials heavy-first
    int h, qt, chunk;
    if (bid < 768) {
        h = bid / 48; int r = bid % 48;
        if (r < 8)       { qt = 8 + r;              chunk = 0; }
        else if (r < 24) { int rs = r - 8;  qt = 16 + (rs >> 1); chunk = rs & 1; }
        else             { int rs = r - 24; qt = 24 + rs / 3;    chunk = rs % 3; }
    } else {
        int p = bid - 768; h = p >> 5; int pb = p & 31;
        int b_ = 7 - (pb >> 2); int a_ = pb & 3;
        qt = 8 * a_ + b_; chunk = a_;
    }
    const int a = qt >> 3, b = qt & 7;
    const int slot = h * SLOTS_PER_HEAD + 4 * a * (a + 1) + b * (a + 1) + chunk;
    const int q0 = qt * 64;
    const int nt = min(8, qt + 1 - chunk * 8);
    const int kstart = chunk * 512;
    const int kvh = h >> 3;
    const float csc = 1.4426950408889634f * 0.08838834764831845f; // log2(e)/sqrt(128)

    const half_t* Kbase = Kr + (size_t)kvh * SEQ * HD;
    const half_t* Vbase = Vt + (size_t)kvh * HD * VTS;

    // Q A-frags for all 64 rows: aq[rg][c], m=lr within row-group rg, k=quad*8 + c*32
    halfx8 aq[4][4];
#pragma unroll
    for (int rg = 0; rg < 4; ++rg) {
        const half_t* qb = qkv + (size_t)(q0 + rg * 16 + lr) * QKVN + h * HD + quad * 8;
#pragma unroll
        for (int c = 0; c < 4; ++c)
            aq[rg][c] = *reinterpret_cast<const halfx8*>(qb + c * 32);
    }
    floatx4 o[4][2] = {};
    floatx4 ol[4] = {};
    halfx8 ones;
#pragma unroll
    for (int j = 0; j < 8; ++j) ones[j] = (lr == 0) ? (half_t)1.0f : (half_t)0.0f;

    // stage K tile 0 into buffer 0 (lane-contig LDS dest; XOR-swizzled global src)
#pragma unroll
    for (int j = 0; j < 4; ++j) {
        int idx = j * 256 + tid;
        int row = idx >> 4, cl = idx & 15;
        int cg = cl ^ (row & 15);
        async_load16(Kbase + (size_t)(kstart + row) * HD + cg * 8, &Ks[0][idx * 8]);
    }
    __syncthreads();

    for (int kt = 0; kt < nt; ++kt) {
        const int k0 = kstart + kt * 64;
        const int buf = kt & 1;
        // ---- prefetch K tile t+1 into other buffer (lands during QK/exp) ----
        if (kt + 1 < nt) {
#pragma unroll
            for (int j = 0; j < 4; ++j) {
                int idx = j * 256 + tid;
                int row = idx >> 4, cl = idx & 15;
                int cg = cl ^ (row & 15);
                async_load16(Kbase + (size_t)(k0 + 64 + row) * HD + cg * 8,
                             &Ks[buf ^ 1][idx * 8]);
            }
        }
        // ---- prefetch V frags for THIS tile into VGPRs (consumed after barrier) ----
        halfx8 vp[2][2];
#pragma unroll
        for (int kc = 0; kc < 2; ++kc)
#pragma unroll
            for (int dd = 0; dd < 2; ++dd)
                vp[kc][dd] = *reinterpret_cast<const halfx8*>(
                    Vbase + (size_t)(wave * 32 + dd * 16 + lr) * VTS + k0 + kc * 32 + quad * 8);
        // ---- seg_end for this wave's key column (issued early, used at mask) ----
        const int col = k0 + wave * 16 + lr;
        const int e = seg_end[col];
        // ---- QK^T: wave's 16 keys vs all 64 rows ----
        floatx4 s[4] = {};
#pragma unroll
        for (int c = 0; c < 4; ++c) {
            halfx8 kb = *reinterpret_cast<const halfx8*>(
                &Ks[buf][(wave * 16 + lr) * 128 + ((quad + 4 * c) ^ lr) * 8]);
#pragma unroll
            for (int rg = 0; rg < 4; ++rg)
                s[rg] = mfma16x16x32(aq[rg][c], kb, s[rg]);
        }
        // ---- mask + exp + write P (C-layout: col=lr -> key, row=quad*4+i) ----
#pragma unroll
        for (int rg = 0; rg < 4; ++rg) {
#pragma unroll
            for (int i = 0; i < 4; ++i) {
                int row = q0 + rg * 16 + quad * 4 + i;
                bool ok = (col <= row) && (row <= e);
                float pp = ok ? exp2f(s[rg][i] * csc) : 0.0f;
                Pl[buf][(rg * 16 + quad * 4 + i) * 72 + wave * 16 + lr] = (half_t)pp;
            }
        }
        __syncthreads();   // single barrier: P visible + all waves' K-DMA drained
        // ---- PV: all 64 rows x wave's 32 dims ----
#pragma unroll
        for (int kc = 0; kc < 2; ++kc) {
            halfx8 pf[4];
#pragma unroll
            for (int rg = 0; rg < 4; ++rg)
                pf[rg] = *reinterpret_cast<const halfx8*>(
                    &Pl[buf][(rg * 16 + lr) * 72 + kc * 32 + quad * 8]);
#pragma unroll
            for (int dd = 0; dd < 2; ++dd)
#pragma unroll
                for (int rg = 0; rg < 4; ++rg)
                    o[rg][dd] = mfma16x16x32(pf[rg], vp[kc][dd], o[rg][dd]);
            if (wave == 3) {
#pragma unroll
                for (int rg = 0; rg < 4; ++rg)
                    ol[rg] = mfma16x16x32(pf[rg], ones, ol[rg]);
            }
        }
    }
    // ---- write partials ----
    half_t* po = part_o + (size_t)slot * (64 * 128);
#pragma unroll
    for (int rg = 0; rg < 4; ++rg)
#pragma unroll
        for (int dd = 0; dd < 2; ++dd)
#pragma unroll
            for (int i = 0; i < 4; ++i)
                po[(rg * 16 + quad * 4 + i) * 128 + wave * 32 + dd * 16 + lr] =
                    (half_t)o[rg][dd][i];
    if (wave == 3 && lr == 0) {
#pragma unroll
        for (int rg = 0; rg < 4; ++rg)
#pragma unroll
            for (int i = 0; i < 4; ++i)
                part_l[slot * 64 + rg * 16 + quad * 4 + i] = ol[rg][i];
    }
    // ---- atomic combine tail: last-arriver for (h,qt) normalizes and writes attnO ----
    __threadfence();                       // release: partials visible device-wide
    __syncthreads();                       // all threads' stores+fences done
    int* flag = (int*)&Ks[0][0];           // Ks dead; reuse as block-wide flag
    if (tid == 0) {
        int old = atomicAdd(&chunk_cnt[h * 32 + qt], 1);
        *flag = (old == a) ? 1 : 0;        // nch = a+1 -> last when old == a
    }
    __syncthreads();
    if (*flag) {
        __threadfence();                   // acquire: see other chunks' partials
        const int base = h * SLOTS_PER_HEAD + 4 * a * (a + 1) + b * (a + 1);
        const int nch = a + 1;
#pragma unroll
        for (int v = 0; v < 4; ++v) {
            int vid = v * 256 + tid;
            int row = vid >> 4;
            int col = (vid & 15) * 8;
            float acc2[8] = {};
            float l = 0.0f;
            for (int c = 0; c < nch; ++c) {
                const half_t* pp = part_o + (size_t)(base + c) * (64 * 128) + row * 128 + col;
                halfx8 pv = *reinterpret_cast<const halfx8*>(pp);
#pragma unroll
                for (int j = 0; j < 8; ++j) acc2[j] += (float)pv[j];
                l += part_l[(base + c) * 64 + row];
            }
            const float rl = 1.0f / l;
            halfx8 outv;
#pragma unroll
            for (int j = 0; j < 8; ++j) outv[j] = (half_t)(acc2[j] * rl);
            *reinterpret_cast<halfx8*>(attnO + (size_t)(q0 + row) * 2048 + h * 128 + col) = outv;
        }
    }
}

extern "C" void kernel_launch(void* const* d_in, const int* in_sizes, int n_in,
                              void* d_out, int out_size, void* d_ws, size_t ws_size,
                              hipStream_t stream) {
    (void)in_sizes; (void)n_in; (void)out_size; (void)ws_size;
    const float* hidden = (const float*)d_in[0];
    const int*   praw   = (const int*)d_in[1];
    const float* w_qkv  = (const float*)d_in[2];
    const float* b_qkv  = (const float*)d_in[3];
    const float* w_o    = (const float*)d_in[4];
    float* out = (float*)d_out;

    char* ws = (char*)d_ws;                        // ~50.7 MB used
    half_t* woT     = (half_t*)(ws + 0);           // [2048][2048] fp16
    half_t* qkvH    = (half_t*)(ws + 8388608);     // [2048][2560] fp16 (Q region only)
    half_t* Kr      = (half_t*)(ws + 18874368);    // [2][2048][128] fp16
    half_t* Vt      = (half_t*)(ws + 19922944);    // [2][128][VTS] fp16 (padded)
    half_t* hiddenH = (half_t*)(ws + 20987904);    // [2048][2048] fp16 (GEMM1 input)
    half_t* attnO   = (half_t*)(ws + 20987904);    // [2048][2048] fp16 (combine out, after GEMM1)
    half_t* wqkvT   = (half_t*)(ws + 29376512);    // [2560][2048] fp16 (dead after GEMM1)
    half_t* part_o  = (half_t*)(ws + 29376512);    // [1280][64][128] fp16 (overlays wqkvT)
    float2* sctab   = (float2*)(ws + 39862272);    // [2048][64] cos/sin — in part_o's tail
                                                   // beyond wqkvT; live only during GEMM1
    float*  part_l  = (float*) (ws + 50348032);    // [1280][64] fp32
    int*    pos_eff = (int*)   (ws + 50675712);
    int*    seg_end = (int*)   (ws + 50684928);    // 2048 ints -> ends 50693120
    int*    chunk_cnt = (int*) (ws + 50693120);    // [512] = 16h x 32qt (zeroed by prep)

    prep_kernel<<<PREP_CVT_BLKS + PREP_T1_BLKS + PREP_T2_BLKS + 1 + PREP_SC_BLKS,
                  256, 0, stream>>>(
        hidden, hiddenH, w_qkv, wqkvT, w_o, woT, praw, pos_eff, seg_end, sctab, chunk_cnt);
    gemm_bt<true, true, true><<<dim3(QKVN / 128, SEQ / 64), 256, 0, stream>>>(
        hiddenH, wqkvT, b_qkv, qkvH, SEQ, QKVN, 2048, sctab, Kr, Vt);
    attn_kernel<<<NQH * SLOTS_PER_HEAD, 256, 0, stream>>>(
        qkvH, Kr, Vt, seg_end, part_o, part_l, chunk_cnt, attnO);
    gemm_bt<false, false, false><<<dim3(2048 / 128, SEQ / 64), 256, 0, stream>>>(
        attnO, woT, nullptr, out, SEQ, 2048, 2048, nullptr, nullptr, nullptr);
}

// Round 12
// 222.601 us; speedup vs baseline: 2.0261x; 2.0261x over previous
//
#include <hip/hip_runtime.h>

typedef _Float16 halfx8 __attribute__((ext_vector_type(8)));
typedef _Float16 halfx4 __attribute__((ext_vector_type(4)));
typedef _Float16 halfx2 __attribute__((ext_vector_type(2)));
typedef float floatx4 __attribute__((ext_vector_type(4)));
typedef _Float16 half_t;

#define SEQ    2048
#define NQH    16
#define NKVH   2
#define HD     128
#define QKVN   2560   // 2048 q + 256 k + 256 v
#define VTS    2080   // Vt row stride in halves (4160 B — breaks 4 KB channel aliasing)
#define SLOTS_PER_HEAD 80    // per head: 48 full 512-key chunks + 32 partial chunks

static __device__ __forceinline__ floatx4 mfma16x16x32(halfx8 a, halfx8 b, floatx4 c) {
    return __builtin_amdgcn_mfma_f32_16x16x32_f16(a, b, c, 0, 0, 0);
}

// async global->LDS, 16B per lane (global_load_lds_dwordx4). LDS dest must be
// wave-uniform base + lane*16 (m104) — global source may be arbitrary per-lane.
typedef __attribute__((address_space(3))) unsigned int lds_uint;
typedef const __attribute__((address_space(1))) unsigned int glob_uint;
static __device__ __forceinline__ void async_load16(const void* g, void* l) {
    __builtin_amdgcn_global_load_lds((glob_uint*)g, (lds_uint*)l, 16, 0, 0);
}

// ---------------- merged prep: cvt + transposes + pos_seg + SINCOS TABLE ----------------
// R11 lesson: per-block device-scope __threadfence (for an atomic combine tail)
// flushes/invalidates L2 per block -> destroys K/V L2 locality kernel-wide
// (attn 56->294 us). Cross-block dataflow stays in a separate dispatch.
#define PREP_CVT_BLKS    4096            // hidden f32->f16: 4096*256 float4
#define PREP_T1_BLKS     (80 * 64)       // w_qkv transpose: C/32 x R/32
#define PREP_T2_BLKS     (64 * 64)       // w_o transpose
#define PREP_SC_BLKS     512             // sincos table: 2048 x 64 entries
__global__ __launch_bounds__(256) void prep_kernel(const float* __restrict__ hidden,
                                                   half_t* __restrict__ hiddenH,
                                                   const float* __restrict__ w_qkv,
                                                   half_t* __restrict__ wqkvT,
                                                   const float* __restrict__ w_o,
                                                   half_t* __restrict__ woT,
                                                   const int* __restrict__ praw,
                                                   int* __restrict__ pos_eff,
                                                   int* __restrict__ seg_end,
                                                   float2* __restrict__ sctab) {
    __shared__ float tile[32][33];
    __shared__ int part[256];
    const int t = threadIdx.x;
    int b = blockIdx.x;
    if (b < PREP_CVT_BLKS) {             // ---- fp32 -> fp16 elementwise ----
        int idx = b * 256 + t;
        float4 v = reinterpret_cast<const float4*>(hidden)[idx];
        halfx4 h = {(half_t)v.x, (half_t)v.y, (half_t)v.z, (half_t)v.w};
        reinterpret_cast<halfx4*>(hiddenH)[idx] = h;
        return;
    }
    b -= PREP_CVT_BLKS;
    if (b < PREP_T1_BLKS + PREP_T2_BLKS) {   // ---- transpose f32 -> f16 ----
        const float* in;
        half_t* out;
        int R, C, bx, by;
        if (b < PREP_T1_BLKS) { in = w_qkv; out = wqkvT; R = 2048; C = QKVN; bx = b % 80; by = b / 80; }
        else { b -= PREP_T1_BLKS; in = w_o; out = woT; R = 2048; C = 2048; bx = b & 63; by = b >> 6; }
        const int tx = t & 31, ty = t >> 5;
        const int r0 = by * 32, c0 = bx * 32;
#pragma unroll
        for (int j = 0; j < 4; ++j)
            tile[ty * 4 + j][tx] = in[(size_t)(r0 + ty * 4 + j) * C + c0 + tx];
        __syncthreads();
        // 16B-per-lane writes: thread t<128 owns out-row c0+cc, 8 r-values
        if (t < 128) {
            const int cc = t >> 2, rB = (t & 3) * 8;
            halfx8 v;
#pragma unroll
            for (int j = 0; j < 8; ++j) v[j] = (half_t)tile[rB + j][cc];
            *reinterpret_cast<halfx8*>(&out[(size_t)(c0 + cc) * R + r0 + rB]) = v;
        }
        return;
    }
    b -= PREP_T1_BLKS + PREP_T2_BLKS;
    if (b >= 1) {                        // ---- sincos table: idx = s*64 + i ----
        int idx = (b - 1) * 256 + t;     // [0, 131072)
        int s = idx >> 6, i = idx & 63;
        const bool is64 = (praw[1] == 0 && praw[2] == 1);
        int p = is64 ? praw[2 * s] : praw[s];
        if (p == -1) p = 0;
        float ang = (float)p * exp2f(-(float)i * (19.931568569324174f / 64.0f));
        float sn, cs;
        sincosf(ang, &sn, &cs);
        sctab[idx] = make_float2(cs, sn);
        return;
    }
    // ---- positions + per-position segment end (single block) ----
    const bool is64 = (praw[1] == 0 && praw[2] == 1);
    const int BIG = 1 << 29;
    int pv[8];
#pragma unroll
    for (int j = 0; j < 8; ++j) {
        int idx = t * 8 + j;
        int p = is64 ? praw[2 * idx] : praw[idx];
        if (p == -1) p = 0;
        pv[j] = p;
        pos_eff[idx] = p;
    }
    int nmin = BIG;
    int loc[8];
#pragma unroll
    for (int j = 7; j >= 0; --j) {
        loc[j] = nmin;
        if (pv[j] == 0) nmin = t * 8 + j;
    }
    part[t] = nmin;
    __syncthreads();
    for (int off = 1; off < 256; off <<= 1) {
        int v = (t + off < 256) ? part[t + off] : BIG;
        __syncthreads();
        part[t] = min(part[t], v);
        __syncthreads();
    }
    int suffix = (t < 255) ? part[t + 1] : BIG;
#pragma unroll
    for (int j = 0; j < 8; ++j) {
        int nxt = min(loc[j], suffix);
        seg_end[t * 8 + j] = min(nxt, SEQ) - 1;
    }
}

// ---------------- fp16 MFMA GEMM, B^T (N-major), 64x128 (MxN) tile, BK=64 ----------------
// v6: BK=64 + both-sides XOR slot-swizzle. v7: FUSE_ROPE epilogue. v8: sincos
// table + Y-major XCD swizzle. R10 datum: both GEMMs < 41 us.
template <bool HAS_BIAS, bool OUT_F16, bool FUSE_ROPE>
__global__ __launch_bounds__(256) void gemm_bt(const half_t* __restrict__ A,
                                               const half_t* __restrict__ BT,
                                               const float* __restrict__ bias,
                                               void* __restrict__ Cout,
                                               int M, int N, int K,
                                               const float2* __restrict__ sctab,
                                               half_t* __restrict__ Kr,
                                               half_t* __restrict__ Vt) {
    __shared__ __align__(16) half_t As[2][64 * 64];    // 16 KB
    __shared__ __align__(16) half_t Bs[2][128 * 64];   // 32 KB
    const int tid = threadIdx.x;
    const int wave = tid >> 6, lane = tid & 63;
    const int lr = lane & 15, quad = lane >> 4;
    // XCD swizzle on linearized block id (nwg multiple of 8: 640, 512).
    // Decode y-major: same-XCD chunk = same bx (B panel) walking by.
    const int nwg = gridDim.x * gridDim.y;
    const int bidl = blockIdx.y * gridDim.x + blockIdx.x;
    const int cpx = nwg >> 3;
    const int swz = (bidl & 7) * cpx + (bidl >> 3);
    const int bx = swz / gridDim.y, by = swz % gridDim.y;
    const int m0 = by * 64, n0 = bx * 128;
    const int rw = (wave & 1) * 32, cw = (wave >> 1) * 64;
    floatx4 acc[2][4] = {};
    auto stage = [&](int kt, int buf) {
        const int k0 = kt * 64;
        // A tile: 64 rows x 8 slots = 512 x 16B
#pragma unroll
        for (int j = 0; j < 2; ++j) {
            int idx = j * 256 + tid;
            int row = idx >> 3, sl = idx & 7;
            async_load16(A + (size_t)(m0 + row) * K + k0 + ((sl ^ (row & 7)) * 8),
                         &As[buf][idx * 8]);
        }
        // B tile: 128 rows x 8 slots = 1024 x 16B
#pragma unroll
        for (int j = 0; j < 4; ++j) {
            int idx = j * 256 + tid;
            int row = idx >> 3, sl = idx & 7;
            async_load16(BT + (size_t)(n0 + row) * K + k0 + ((sl ^ (row & 7)) * 8),
                         &Bs[buf][idx * 8]);
        }
    };
    const int NT = K >> 6;
    stage(0, 0);
    __syncthreads();
    for (int t = 0; t < NT; ++t) {
        const int buf = t & 1;
        if (t + 1 < NT) stage(t + 1, buf ^ 1);   // prefetch lands during MFMA
#pragma unroll
        for (int ks = 0; ks < 2; ++ks) {
            halfx8 af[2], bfr[4];
#pragma unroll
            for (int q2 = 0; q2 < 2; ++q2)
                af[q2] = *reinterpret_cast<const halfx8*>(
                    &As[buf][(rw + q2 * 16 + lr) * 64 + (((ks << 2) + quad) ^ (lr & 7)) * 8]);
#pragma unroll
            for (int q4 = 0; q4 < 4; ++q4)
                bfr[q4] = *reinterpret_cast<const halfx8*>(
                    &Bs[buf][(cw + q4 * 16 + lr) * 64 + (((ks << 2) + quad) ^ (lr & 7)) * 8]);
#pragma unroll
            for (int im = 0; im < 2; ++im)
#pragma unroll
                for (int in = 0; in < 4; ++in)
                    acc[im][in] = mfma16x16x32(af[im], bfr[in], acc[im][in]);
        }
        // single barrier: drains this iter's prefetch + guards buffer reuse
        __syncthreads();
    }
    if (!FUSE_ROPE) {
#pragma unroll
        for (int in = 0; in < 4; ++in) {
            const int col = n0 + cw + in * 16 + lr;
            float bv = 0.0f;
            if (HAS_BIAS) bv = bias[col];
#pragma unroll
            for (int im = 0; im < 2; ++im) {
#pragma unroll
                for (int r = 0; r < 4; ++r) {
                    int rowg = m0 + rw + im * 16 + quad * 4 + r;
                    float v = acc[im][in][r] + bv;
                    if (OUT_F16)
                        ((half_t*)Cout)[(size_t)rowg * N + col] = (half_t)v;
                    else
                        ((float*)Cout)[(size_t)rowg * N + col] = v;
                }
            }
        }
    } else {
        const int region = n0 >> 7;          // 0..15 Q, 16..17 K, 18..19 V (uniform/block)
        int rowg_[2][4];
#pragma unroll
        for (int im = 0; im < 2; ++im)
#pragma unroll
            for (int r = 0; r < 4; ++r)
                rowg_[im][r] = m0 + rw + im * 16 + quad * 4 + r;
#pragma unroll
        for (int in = 0; in < 4; ++in) {
            const int col = n0 + cw + in * 16 + lr;
            const float bv = bias[col];
            if (region < 18) {
                // rope: pair index shared by lanes (lr, lr^1); table load, no trig
                const int fidx = (col & 127) >> 1;
#pragma unroll
                for (int im = 0; im < 2; ++im) {
#pragma unroll
                    for (int r = 0; r < 4; ++r) {
                        float v = acc[im][in][r] + bv;
                        float other = __shfl_xor(v, 1, 64);
                        float2 sc = sctab[rowg_[im][r] * 64 + fidx];
                        float res = (lr & 1) ? (other * sc.y + v * sc.x)
                                             : (v * sc.x - other * sc.y);
                        if (region < 16)
                            ((half_t*)Cout)[(size_t)rowg_[im][r] * N + col] = (half_t)res;
                        else
                            Kr[(size_t)(region - 16) * SEQ * HD +
                               (size_t)rowg_[im][r] * HD + (col & 127)] = (half_t)res;
                    }
                }
            } else {
                // V: raw (biased) values, transposed into Vt[d][s]; pack 4 rows = 8B
                half_t* vb = Vt + (size_t)(region - 18) * HD * VTS + (size_t)(col & 127) * VTS;
#pragma unroll
                for (int im = 0; im < 2; ++im) {
                    halfx4 pk;
#pragma unroll
                    for (int r = 0; r < 4; ++r) pk[r] = (half_t)(acc[im][in][r] + bv);
                    *reinterpret_cast<halfx4*>(&vb[m0 + rw + im * 16 + quad * 4]) = pk;
                }
            }
        }
    }
}

// ---------------- flash attention v9: swapped QK^T + packed P-write ----------------
// v5 structure (single dispatch, 56.4 us baseline) with the T12-style operand
// swap: s[rg] = mfma(kb, aq[rg]) computes scores^T, so the C-layout gives each
// thread 4 CONSECUTIVE KEYS (quad*4+i) for one q-row (rg*16+lr). P-write becomes
// 4x ds_write_b64 (halfx4) instead of 16x scalar ds_write_u16. Pl layout, PV
// reads, and the ones-MFMA l-sum are unchanged. seg_end is one aligned int4
// load (4 consecutive keys). VGPR watch: +3 transient regs; if VGPR_Count >128
// in counters (R3 cliff), revert.
__global__ __launch_bounds__(256) void attn_kernel(const half_t* __restrict__ qkv,
                                                   const half_t* __restrict__ Kr,
                                                   const half_t* __restrict__ Vt,
                                                   const int* __restrict__ seg_end,
                                                   half_t* __restrict__ part_o,
                                                   float* __restrict__ part_l) {
    __shared__ __align__(16) half_t Ks[2][64 * 128];  // 2x16 KB, XOR-swizzled
    __shared__ __align__(16) half_t Pl[2][64 * 72];   // 2x9 KB, padded stride
    const int tid = threadIdx.x;
    const int wave = tid >> 6, lane = tid & 63;
    const int lr = lane & 15, quad = lane >> 4;
    const int bid = blockIdx.x;
    // dispatch decode: 768 full 8-tile chunks first, then partials heavy-first
    int h, qt, chunk;
    if (bid < 768) {
        h = bid / 48; int r = bid % 48;
        if (r < 8)       { qt = 8 + r;              chunk = 0; }
        else if (r < 24) { int rs = r - 8;  qt = 16 + (rs >> 1); chunk = rs & 1; }
        else             { int rs = r - 24; qt = 24 + rs / 3;    chunk = rs % 3; }
    } else {
        int p = bid - 768; h = p >> 5; int pb = p & 31;
        int b_ = 7 - (pb >> 2); int a_ = pb & 3;
        qt = 8 * a_ + b_; chunk = a_;
    }
    const int a = qt >> 3, b = qt & 7;
    const int slot = h * SLOTS_PER_HEAD + 4 * a * (a + 1) + b * (a + 1) + chunk;
    const int q0 = qt * 64;
    const int nt = min(8, qt + 1 - chunk * 8);
    const int kstart = chunk * 512;
    const int kvh = h >> 3;
    const float csc = 1.4426950408889634f * 0.08838834764831845f; // log2(e)/sqrt(128)

    const half_t* Kbase = Kr + (size_t)kvh * SEQ * HD;
    const half_t* Vbase = Vt + (size_t)kvh * HD * VTS;

    // Q A-frags for all 64 rows: aq[rg][c], m=lr within row-group rg, k=quad*8 + c*32
    halfx8 aq[4][4];
#pragma unroll
    for (int rg = 0; rg < 4; ++rg) {
        const half_t* qb = qkv + (size_t)(q0 + rg * 16 + lr) * QKVN + h * HD + quad * 8;
#pragma unroll
        for (int c = 0; c < 4; ++c)
            aq[rg][c] = *reinterpret_cast<const halfx8*>(qb + c * 32);
    }
    floatx4 o[4][2] = {};
    floatx4 ol[4] = {};
    halfx8 ones;
#pragma unroll
    for (int j = 0; j < 8; ++j) ones[j] = (lr == 0) ? (half_t)1.0f : (half_t)0.0f;

    // stage K tile 0 into buffer 0 (lane-contig LDS dest; XOR-swizzled global src)
#pragma unroll
    for (int j = 0; j < 4; ++j) {
        int idx = j * 256 + tid;
        int row = idx >> 4, cl = idx & 15;
        int cg = cl ^ (row & 15);
        async_load16(Kbase + (size_t)(kstart + row) * HD + cg * 8, &Ks[0][idx * 8]);
    }
    __syncthreads();

    for (int kt = 0; kt < nt; ++kt) {
        const int k0 = kstart + kt * 64;
        const int buf = kt & 1;
        // ---- prefetch K tile t+1 into other buffer (lands during QK/exp) ----
        if (kt + 1 < nt) {
#pragma unroll
            for (int j = 0; j < 4; ++j) {
                int idx = j * 256 + tid;
                int row = idx >> 4, cl = idx & 15;
                int cg = cl ^ (row & 15);
                async_load16(Kbase + (size_t)(k0 + 64 + row) * HD + cg * 8,
                             &Ks[buf ^ 1][idx * 8]);
            }
        }
        // ---- prefetch V frags for THIS tile into VGPRs (consumed after barrier) ----
        halfx8 vp[2][2];
#pragma unroll
        for (int kc = 0; kc < 2; ++kc)
#pragma unroll
            for (int dd = 0; dd < 2; ++dd)
                vp[kc][dd] = *reinterpret_cast<const halfx8*>(
                    Vbase + (size_t)(wave * 32 + dd * 16 + lr) * VTS + k0 + kc * 32 + quad * 8);
        // ---- seg_end for this thread's 4 consecutive keys (aligned int4) ----
        const int colb = k0 + wave * 16 + quad * 4;
        const int4 e4 = *reinterpret_cast<const int4*>(&seg_end[colb]);
        // ---- QK^T swapped: D[key][qrow]; kb as A-operand, aq as B-operand ----
        floatx4 s[4] = {};
#pragma unroll
        for (int c = 0; c < 4; ++c) {
            halfx8 kb = *reinterpret_cast<const halfx8*>(
                &Ks[buf][(wave * 16 + lr) * 128 + ((quad + 4 * c) ^ lr) * 8]);
#pragma unroll
            for (int rg = 0; rg < 4; ++rg)
                s[rg] = mfma16x16x32(kb, aq[rg][c], s[rg]);
        }
        // ---- mask + exp + PACKED P write: thread holds keys colb+i for qrow rg*16+lr ----
#pragma unroll
        for (int rg = 0; rg < 4; ++rg) {
            const int qrow = q0 + rg * 16 + lr;
            halfx4 pk;
#pragma unroll
            for (int i = 0; i < 4; ++i) {
                int key = colb + i;
                int e = (i == 0) ? e4.x : (i == 1) ? e4.y : (i == 2) ? e4.z : e4.w;
                bool ok = (key <= qrow) && (qrow <= e);
                pk[i] = ok ? (half_t)exp2f(s[rg][i] * csc) : (half_t)0.0f;
            }
            *reinterpret_cast<halfx4*>(
                &Pl[buf][(rg * 16 + lr) * 72 + wave * 16 + quad * 4]) = pk;
        }
        __syncthreads();   // single barrier: P visible + all waves' K-DMA drained
        // ---- PV: all 64 rows x wave's 32 dims (unchanged) ----
#pragma unroll
        for (int kc = 0; kc < 2; ++kc) {
            halfx8 pf[4];
#pragma unroll
            for (int rg = 0; rg < 4; ++rg)
                pf[rg] = *reinterpret_cast<const halfx8*>(
                    &Pl[buf][(rg * 16 + lr) * 72 + kc * 32 + quad * 8]);
#pragma unroll
            for (int dd = 0; dd < 2; ++dd)
#pragma unroll
                for (int rg = 0; rg < 4; ++rg)
                    o[rg][dd] = mfma16x16x32(pf[rg], vp[kc][dd], o[rg][dd]);
            if (wave == 3) {
#pragma unroll
                for (int rg = 0; rg < 4; ++rg)
                    ol[rg] = mfma16x16x32(pf[rg], ones, ol[rg]);
            }
        }
    }
    // ---- write partials ----
    half_t* po = part_o + (size_t)slot * (64 * 128);
#pragma unroll
    for (int rg = 0; rg < 4; ++rg)
#pragma unroll
        for (int dd = 0; dd < 2; ++dd)
#pragma unroll
            for (int i = 0; i < 4; ++i)
                po[(rg * 16 + quad * 4 + i) * 128 + wave * 32 + dd * 16 + lr] =
                    (half_t)o[rg][dd][i];
    if (wave == 3 && lr == 0) {
#pragma unroll
        for (int rg = 0; rg < 4; ++rg)
#pragma unroll
            for (int i = 0; i < 4; ++i)
                part_l[slot * 64 + rg * 16 + quad * 4 + i] = ol[rg][i];
    }
}

// ---------------- combine partials: sum chunks, normalize, write attnO ----------------
__global__ __launch_bounds__(256) void combine_kernel(const half_t* __restrict__ part_o,
                                                      const float* __restrict__ part_l,
                                                      half_t* __restrict__ attnO) {
    const int h  = blockIdx.x >> 5;
    const int qt = blockIdx.x & 31;
    const int a = qt >> 3, b = qt & 7;
    const int base = h * SLOTS_PER_HEAD + 4 * a * (a + 1) + b * (a + 1);
    const int nch = a + 1;
    const int tid = threadIdx.x;
#pragma unroll
    for (int v = 0; v < 4; ++v) {
        int vid = v * 256 + tid;
        int row = vid >> 4;
        int col = (vid & 15) * 8;
        float acc[8] = {};
        float l = 0.0f;
        for (int c = 0; c < nch; ++c) {
            const half_t* po = part_o + (size_t)(base + c) * (64 * 128) + row * 128 + col;
            halfx8 pv = *reinterpret_cast<const halfx8*>(po);
#pragma unroll
            for (int j = 0; j < 8; ++j) acc[j] += (float)pv[j];
            l += part_l[(base + c) * 64 + row];
        }
        const float rl = 1.0f / l;
        halfx8 outv;
#pragma unroll
        for (int j = 0; j < 8; ++j) outv[j] = (half_t)(acc[j] * rl);
        *reinterpret_cast<halfx8*>(attnO + (size_t)(qt * 64 + row) * 2048 + h * 128 + col) = outv;
    }
}

extern "C" void kernel_launch(void* const* d_in, const int* in_sizes, int n_in,
                              void* d_out, int out_size, void* d_ws, size_t ws_size,
                              hipStream_t stream) {
    (void)in_sizes; (void)n_in; (void)out_size; (void)ws_size;
    const float* hidden = (const float*)d_in[0];
    const int*   praw   = (const int*)d_in[1];
    const float* w_qkv  = (const float*)d_in[2];
    const float* b_qkv  = (const float*)d_in[3];
    const float* w_o    = (const float*)d_in[4];
    float* out = (float*)d_out;

    char* ws = (char*)d_ws;                        // ~50.7 MB used
    half_t* woT     = (half_t*)(ws + 0);           // [2048][2048] fp16
    half_t* qkvH    = (half_t*)(ws + 8388608);     // [2048][2560] fp16 (Q region only)
    half_t* Kr      = (half_t*)(ws + 18874368);    // [2][2048][128] fp16
    half_t* Vt      = (half_t*)(ws + 19922944);    // [2][128][VTS] fp16 (padded)
    half_t* hiddenH = (half_t*)(ws + 20987904);    // [2048][2048] fp16 (GEMM1 input)
    half_t* attnO   = (half_t*)(ws + 20987904);    // [2048][2048] fp16 (combine out, after GEMM1)
    half_t* wqkvT   = (half_t*)(ws + 29376512);    // [2560][2048] fp16 (dead after GEMM1)
    half_t* part_o  = (half_t*)(ws + 29376512);    // [1280][64][128] fp16 (overlays wqkvT)
    float2* sctab   = (float2*)(ws + 39862272);    // [2048][64] cos/sin — in part_o's tail
                                                   // beyond wqkvT; live only during GEMM1
    float*  part_l  = (float*) (ws + 50348032);    // [1280][64] fp32
    int*    pos_eff = (int*)   (ws + 50675712);
    int*    seg_end = (int*)   (ws + 50684928);

    prep_kernel<<<PREP_CVT_BLKS + PREP_T1_BLKS + PREP_T2_BLKS + 1 + PREP_SC_BLKS,
                  256, 0, stream>>>(
        hidden, hiddenH, w_qkv, wqkvT, w_o, woT, praw, pos_eff, seg_end, sctab);
    gemm_bt<true, true, true><<<dim3(QKVN / 128, SEQ / 64), 256, 0, stream>>>(
        hiddenH, wqkvT, b_qkv, qkvH, SEQ, QKVN, 2048, sctab, Kr, Vt);
    attn_kernel<<<NQH * SLOTS_PER_HEAD, 256, 0, stream>>>(qkvH, Kr, Vt, seg_end, part_o, part_l);
    combine_kernel<<<512, 256, 0, stream>>>(part_o, part_l, attnO);
    gemm_bt<false, false, false><<<dim3(2048 / 128, SEQ / 64), 256, 0, stream>>>(
        attnO, woT, nullptr, out, SEQ, 2048, 2048, nullptr, nullptr, nullptr);
}